// Round 3
// baseline (865.582 us; speedup 1.0000x reference)
//
#include <hip/hip_runtime.h>

#define N_NODES 100000
#define N_EDGES 3200000

__device__ inline ushort f2bf(float f) {  // RNE f32 -> bf16
    uint u = __float_as_uint(f);
    return (ushort)((u + 0x7fffu + ((u >> 16) & 1u)) >> 16);
}

// ---------------- CSR build ----------------

__global__ void hist_kernel(const int* __restrict__ dst, int* __restrict__ cnt, int e) {
    int i = blockIdx.x * blockDim.x + threadIdx.x;
    if (i < e) atomicAdd(&cnt[dst[i]], 1);
}

__global__ void scan1_kernel(const int* __restrict__ cnt, int* __restrict__ rp,
                             int* __restrict__ bsum, int n) {
    __shared__ int tile[1024];
    int tx = threadIdx.x;
    int i = blockIdx.x * 1024 + tx;
    int v = (i < n) ? cnt[i] : 0;
    tile[tx] = v;
    __syncthreads();
    #pragma unroll
    for (int off = 1; off < 1024; off <<= 1) {
        int t = (tx >= off) ? tile[tx - off] : 0;
        __syncthreads();
        tile[tx] += t;
        __syncthreads();
    }
    if (i < n) rp[i] = tile[tx] - v;  // exclusive within block
    if (tx == 1023) bsum[blockIdx.x] = tile[1023];
}

__global__ void scan2_kernel(int* __restrict__ bsum, int* __restrict__ rp, int nb, int n) {
    __shared__ int tile[128];
    int tx = threadIdx.x;
    int v = (tx < nb) ? bsum[tx] : 0;
    tile[tx] = v;
    __syncthreads();
    #pragma unroll
    for (int off = 1; off < 128; off <<= 1) {
        int t = (tx >= off) ? tile[tx - off] : 0;
        __syncthreads();
        tile[tx] += t;
        __syncthreads();
    }
    if (tx < nb) bsum[tx] = tile[tx] - v;  // exclusive
    if (tx == 127) rp[n] = tile[127];
}

__global__ void scan3_kernel(int* __restrict__ rp, const int* __restrict__ bsum, int n) {
    int i = blockIdx.x * 1024 + threadIdx.x;
    if (i < n) rp[i] += bsum[blockIdx.x];
}

__global__ void scatter_kernel(const int* __restrict__ dst, const int* __restrict__ src,
                               const float* __restrict__ w, int e,
                               const int* __restrict__ rp, int* __restrict__ fill,
                               int2* __restrict__ ep) {
    int i = blockIdx.x * blockDim.x + threadIdx.x;
    if (i < e) {
        int d = dst[i];
        int pos = rp[d] + atomicAdd(&fill[d], 1);
        int2 p;
        p.x = src[i];
        p.y = __float_as_int(w[i]);
        ep[pos] = p;
    }
}

// ---------------- cast x -> bf16 ----------------

__global__ void cast_bf16_kernel(const float* __restrict__ in, ushort* __restrict__ out, int n8) {
    int i = blockIdx.x * blockDim.x + threadIdx.x;
    if (i >= n8) return;
    size_t base = (size_t)i * 8;
    float4 a = *reinterpret_cast<const float4*>(in + base);
    float4 b = *reinterpret_cast<const float4*>(in + base + 4);
    ushort4 o0, o1;
    o0.x = f2bf(a.x); o0.y = f2bf(a.y); o0.z = f2bf(a.z); o0.w = f2bf(a.w);
    o1.x = f2bf(b.x); o1.y = f2bf(b.y); o1.z = f2bf(b.z); o1.w = f2bf(b.w);
    *reinterpret_cast<ushort4*>(out + base) = o0;
    *reinterpret_cast<ushort4*>(out + base + 4) = o1;
}

// ---------------- CSR SpMM (bf16 gathers, shfl-broadcast edges) ----------------
// one wave per dst row; lanes cooperatively load up to 64 edges, broadcast via shfl;
// the only in-loop memory op is the independent feature gather.

__global__ void spmm_x_bf16(const int2* __restrict__ ep, const int* __restrict__ rp,
                            const uint* __restrict__ x2 /* [N][64] bf16 pairs */,
                            float* __restrict__ out, int n) {
    int row = blockIdx.x * 4 + (threadIdx.x >> 6);
    if (row >= n) return;
    int lane = threadIdx.x & 63;
    int beg = rp[row], end = rp[row + 1];
    float ax = 0.f, ay = 0.f;
    for (int c = beg; c < end; c += 64) {
        int m = end - c; if (m > 64) m = 64;
        int2 p = (c + lane < end) ? ep[c + lane] : make_int2(0, 0);
        #pragma unroll 8
        for (int j = 0; j < m; ++j) {
            int s = __shfl(p.x, j);
            float wv = __int_as_float(__shfl(p.y, j));
            uint v = x2[(size_t)s * 64 + lane];
            ax += wv * __uint_as_float(v << 16);
            ay += wv * __uint_as_float(v & 0xffff0000u);
        }
    }
    float2 r; r.x = ax; r.y = ay;
    *reinterpret_cast<float2*>(out + (size_t)row * 128 + lane * 2) = r;
}

__global__ void spmm_g_bf16(const int2* __restrict__ ep, const int* __restrict__ rp,
                            const ushort* __restrict__ g2 /* [N][64] bf16 */,
                            const float* __restrict__ bias, float* __restrict__ out, int n) {
    int row = blockIdx.x * 4 + (threadIdx.x >> 6);
    if (row >= n) return;
    int lane = threadIdx.x & 63;
    int beg = rp[row], end = rp[row + 1];
    float acc = 0.f;
    for (int c = beg; c < end; c += 64) {
        int m = end - c; if (m > 64) m = 64;
        int2 p = (c + lane < end) ? ep[c + lane] : make_int2(0, 0);
        #pragma unroll 8
        for (int j = 0; j < m; ++j) {
            int s = __shfl(p.x, j);
            float wv = __int_as_float(__shfl(p.y, j));
            uint v = (uint)g2[(size_t)s * 64 + lane];
            acc += wv * __uint_as_float(v << 16);
        }
    }
    out[(size_t)row * 64 + lane] = acc + bias[lane];
}

// ---------------- dense GEMMs (f32 vector ALU; no fp32 MFMA on CDNA4) ----------------

// s[N,128] @ W1[128,256] + b1, relu -> h[N,256].  32 rows/block, 256 threads.
__global__ void gemm1_kernel(const float* __restrict__ A, const float* __restrict__ W,
                             const float* __restrict__ bias, float* __restrict__ out) {
    __shared__ float4 tile[32][32];  // 32 rows x 128 k  (16 KiB)
    int tx = threadIdx.x;
    int row0 = blockIdx.x * 32;
    #pragma unroll
    for (int i = 0; i < 4; ++i) {
        int idx = i * 256 + tx;
        int r = idx >> 5, c = idx & 31;
        tile[r][c] = *reinterpret_cast<const float4*>(A + (size_t)(row0 + r) * 128 + c * 4);
    }
    __syncthreads();
    int w = tx >> 6;   // wave -> rows w*8..w*8+7
    int l = tx & 63;   // cols 4l..4l+3
    float4 acc[8];
    #pragma unroll
    for (int r = 0; r < 8; ++r) { acc[r].x = acc[r].y = acc[r].z = acc[r].w = 0.f; }
    for (int k4 = 0; k4 < 32; ++k4) {
        float4 wv0 = *reinterpret_cast<const float4*>(W + (size_t)(k4 * 4 + 0) * 256 + l * 4);
        float4 wv1 = *reinterpret_cast<const float4*>(W + (size_t)(k4 * 4 + 1) * 256 + l * 4);
        float4 wv2 = *reinterpret_cast<const float4*>(W + (size_t)(k4 * 4 + 2) * 256 + l * 4);
        float4 wv3 = *reinterpret_cast<const float4*>(W + (size_t)(k4 * 4 + 3) * 256 + l * 4);
        #pragma unroll
        for (int r = 0; r < 8; ++r) {
            float4 a = tile[w * 8 + r][k4];  // wave-uniform -> LDS broadcast
            acc[r].x += a.x * wv0.x + a.y * wv1.x + a.z * wv2.x + a.w * wv3.x;
            acc[r].y += a.x * wv0.y + a.y * wv1.y + a.z * wv2.y + a.w * wv3.y;
            acc[r].z += a.x * wv0.z + a.y * wv1.z + a.z * wv2.z + a.w * wv3.z;
            acc[r].w += a.x * wv0.w + a.y * wv1.w + a.z * wv2.w + a.w * wv3.w;
        }
    }
    float4 bv = *reinterpret_cast<const float4*>(bias + l * 4);
    #pragma unroll
    for (int r = 0; r < 8; ++r) {
        float4 v;
        v.x = fmaxf(acc[r].x + bv.x, 0.f);
        v.y = fmaxf(acc[r].y + bv.y, 0.f);
        v.z = fmaxf(acc[r].z + bv.z, 0.f);
        v.w = fmaxf(acc[r].w + bv.w, 0.f);
        *reinterpret_cast<float4*>(out + (size_t)(row0 + w * 8 + r) * 256 + l * 4) = v;
    }
}

// h[N,256] @ W2[256,64] -> g[N,64] in bf16.  32 rows/block, 256 threads.
__global__ void gemm2_kernel(const float* __restrict__ A, const float* __restrict__ W,
                             ushort* __restrict__ out) {
    __shared__ float4 tile[32][65];  // 32 rows x 256 k, padded
    int tx = threadIdx.x;
    int row0 = blockIdx.x * 32;
    #pragma unroll
    for (int i = 0; i < 8; ++i) {
        int idx = i * 256 + tx;
        int r = idx >> 6, c = idx & 63;
        tile[r][c] = *reinterpret_cast<const float4*>(A + (size_t)(row0 + r) * 256 + c * 4);
    }
    __syncthreads();
    int w = tx >> 6;
    int l = tx & 63;
    int cg = (l & 15) * 4;  // cols cg..cg+3
    int s = l >> 4;         // row-sub 0..3
    int rbase = w * 8 + s * 2;
    float4 acc[2];
    #pragma unroll
    for (int r = 0; r < 2; ++r) { acc[r].x = acc[r].y = acc[r].z = acc[r].w = 0.f; }
    for (int k4 = 0; k4 < 64; ++k4) {
        float4 wv0 = *reinterpret_cast<const float4*>(W + (size_t)(k4 * 4 + 0) * 64 + cg);
        float4 wv1 = *reinterpret_cast<const float4*>(W + (size_t)(k4 * 4 + 1) * 64 + cg);
        float4 wv2 = *reinterpret_cast<const float4*>(W + (size_t)(k4 * 4 + 2) * 64 + cg);
        float4 wv3 = *reinterpret_cast<const float4*>(W + (size_t)(k4 * 4 + 3) * 64 + cg);
        #pragma unroll
        for (int r = 0; r < 2; ++r) {
            float4 a = tile[rbase + r][k4];
            acc[r].x += a.x * wv0.x + a.y * wv1.x + a.z * wv2.x + a.w * wv3.x;
            acc[r].y += a.x * wv0.y + a.y * wv1.y + a.z * wv2.y + a.w * wv3.y;
            acc[r].z += a.x * wv0.z + a.y * wv1.z + a.z * wv2.z + a.w * wv3.z;
            acc[r].w += a.x * wv0.w + a.y * wv1.w + a.z * wv2.w + a.w * wv3.w;
        }
    }
    #pragma unroll
    for (int r = 0; r < 2; ++r) {
        ushort4 o;
        o.x = f2bf(acc[r].x); o.y = f2bf(acc[r].y);
        o.z = f2bf(acc[r].z); o.w = f2bf(acc[r].w);
        *reinterpret_cast<ushort4*>(out + (size_t)(row0 + rbase + r) * 64 + cg) = o;
    }
}

// ---------------- launch ----------------

extern "C" void kernel_launch(void* const* d_in, const int* in_sizes, int n_in,
                              void* d_out, int out_size, void* d_ws, size_t ws_size,
                              hipStream_t stream) {
    const float* x     = (const float*)d_in[0];
    const int*   ei    = (const int*)d_in[1];
    const float* ew_in = (const float*)d_in[2];
    const float* W1    = (const float*)d_in[3];
    const float* b1    = (const float*)d_in[4];
    const float* W2    = (const float*)d_in[5];
    const float* b2    = (const float*)d_in[6];
    float* outp = (float*)d_out;

    const int n = N_NODES, e = N_EDGES;
    const int* dst = ei;       // edge_index[0]
    const int* src = ei + e;   // edge_index[1]

    char* ws = (char*)d_ws;
    size_t off = 0;
    auto alloc = [&](size_t bytes) {
        void* p = ws + off;
        off += (bytes + 255) & ~size_t(255);
        return p;
    };
    int2*  ep   = (int2*)alloc(sizeof(int2) * (size_t)e);
    int*   cnt  = (int*)alloc(sizeof(int) * (size_t)n * 2);  // cnt + fill
    int*   fill = cnt + n;
    int*   rp   = (int*)alloc(sizeof(int) * (size_t)(n + 1));
    int*   bsum = (int*)alloc(sizeof(int) * 256);
    float* sbuf = (float*)alloc(sizeof(float) * (size_t)n * 128);
    float* hbuf = (float*)alloc(sizeof(float) * (size_t)n * 256);
    ushort* x2  = (ushort*)hbuf;  // x-bf16 lives in hbuf region; dead before gemm1 writes h
    ushort* g2  = (ushort*)sbuf;  // g-bf16 reuses sbuf (s dead after gemm1)

    const int nb = (n + 1023) / 1024;  // 98

    hipMemsetAsync(cnt, 0, sizeof(int) * (size_t)n * 2, stream);
    cast_bf16_kernel<<<(n * 128 / 8 + 255) / 256, 256, 0, stream>>>(x, x2, n * 128 / 8);
    hist_kernel<<<(e + 255) / 256, 256, 0, stream>>>(dst, cnt, e);
    scan1_kernel<<<nb, 1024, 0, stream>>>(cnt, rp, bsum, n);
    scan2_kernel<<<1, 128, 0, stream>>>(bsum, rp, nb, n);
    scan3_kernel<<<nb, 1024, 0, stream>>>(rp, bsum, n);
    scatter_kernel<<<(e + 255) / 256, 256, 0, stream>>>(dst, src, ew_in, e, rp, fill, ep);

    // layer 1 (restructured): s = A @ x ; h = relu(s @ W1 + b1)
    spmm_x_bf16<<<(n + 3) / 4, 256, 0, stream>>>(ep, rp, (const uint*)x2, sbuf, n);
    gemm1_kernel<<<n / 32, 256, 0, stream>>>(sbuf, W1, b1, hbuf);

    // layer 2: g = h @ W2 (bf16) ; out = A @ g + b2
    gemm2_kernel<<<n / 32, 256, 0, stream>>>(hbuf, W2, g2);
    spmm_g_bf16<<<(n + 3) / 4, 256, 0, stream>>>(ep, rp, g2, b2, outp, n);
}

// Round 4
// 680.422 us; speedup vs baseline: 1.2721x; 1.2721x over previous
//
#include <hip/hip_runtime.h>

#define N_NODES 100000
#define N_EDGES 3200000

__device__ inline ushort f2bf(float f) {  // RNE f32 -> bf16
    uint u = __float_as_uint(f);
    return (ushort)((u + 0x7fffu + ((u >> 16) & 1u)) >> 16);
}

// ---------------- CSR build ----------------

__global__ void hist_kernel(const int* __restrict__ dst, int* __restrict__ cnt, int e) {
    int i = blockIdx.x * blockDim.x + threadIdx.x;
    if (i < e) atomicAdd(&cnt[dst[i]], 1);
}

__global__ void scan1_kernel(const int* __restrict__ cnt, int* __restrict__ rp,
                             int* __restrict__ bsum, int n) {
    __shared__ int tile[1024];
    int tx = threadIdx.x;
    int i = blockIdx.x * 1024 + tx;
    int v = (i < n) ? cnt[i] : 0;
    tile[tx] = v;
    __syncthreads();
    #pragma unroll
    for (int off = 1; off < 1024; off <<= 1) {
        int t = (tx >= off) ? tile[tx - off] : 0;
        __syncthreads();
        tile[tx] += t;
        __syncthreads();
    }
    if (i < n) rp[i] = tile[tx] - v;  // exclusive within block
    if (tx == 1023) bsum[blockIdx.x] = tile[1023];
}

__global__ void scan2_kernel(int* __restrict__ bsum, int* __restrict__ rp, int nb, int n) {
    __shared__ int tile[128];
    int tx = threadIdx.x;
    int v = (tx < nb) ? bsum[tx] : 0;
    tile[tx] = v;
    __syncthreads();
    #pragma unroll
    for (int off = 1; off < 128; off <<= 1) {
        int t = (tx >= off) ? tile[tx - off] : 0;
        __syncthreads();
        tile[tx] += t;
        __syncthreads();
    }
    if (tx < nb) bsum[tx] = tile[tx] - v;  // exclusive
    if (tx == 127) rp[n] = tile[127];
}

__global__ void scan3_kernel(int* __restrict__ rp, const int* __restrict__ bsum, int n) {
    int i = blockIdx.x * 1024 + threadIdx.x;
    if (i < n) rp[i] += bsum[blockIdx.x];
}

__global__ void scatter_kernel(const int* __restrict__ dst, const int* __restrict__ src,
                               const float* __restrict__ w, int e,
                               const int* __restrict__ rp, int* __restrict__ fill,
                               int2* __restrict__ ep) {
    int i = blockIdx.x * blockDim.x + threadIdx.x;
    if (i < e) {
        int d = dst[i];
        int pos = rp[d] + atomicAdd(&fill[d], 1);
        int2 p;
        p.x = src[i];
        p.y = __float_as_int(w[i]);
        ep[pos] = p;
    }
}

// ---------------- cast x -> bf16 ----------------

__global__ void cast_bf16_kernel(const float* __restrict__ in, ushort* __restrict__ out, int n8) {
    int i = blockIdx.x * blockDim.x + threadIdx.x;
    if (i >= n8) return;
    size_t base = (size_t)i * 8;
    float4 a = *reinterpret_cast<const float4*>(in + base);
    float4 b = *reinterpret_cast<const float4*>(in + base + 4);
    ushort4 o0, o1;
    o0.x = f2bf(a.x); o0.y = f2bf(a.y); o0.z = f2bf(a.z); o0.w = f2bf(a.w);
    o1.x = f2bf(b.x); o1.y = f2bf(b.y); o1.z = f2bf(b.z); o1.w = f2bf(b.w);
    *reinterpret_cast<ushort4*>(out + base) = o0;
    *reinterpret_cast<ushort4*>(out + base + 4) = o1;
}

// ---------------- CSR SpMM (wide bf16 gathers, group-per-edge) ----------------
// spmm_x: row = 128 bf16 = 256B = 16 lanes x uint4 -> 4 edges per wave-instruction.
// (src,w) loaded group-uniform straight from ep (L1 + same-address broadcast); no LDS ops.

__global__ void spmm_x_bf16(const int2* __restrict__ ep, const int* __restrict__ rp,
                            const uint4* __restrict__ x4 /* [N][16] */,
                            float* __restrict__ out, int n) {
    int row = blockIdx.x * 4 + (threadIdx.x >> 6);
    if (row >= n) return;
    int lane = threadIdx.x & 63;
    int g = lane >> 4;   // edge-group 0..3
    int q = lane & 15;   // 16B chunk within row
    int beg = rp[row], end = rp[row + 1];
    if (end <= beg) {
        if (lane < 16) {
            float4 z = {0.f, 0.f, 0.f, 0.f};
            *reinterpret_cast<float4*>(out + (size_t)row * 128 + q * 8) = z;
            *reinterpret_cast<float4*>(out + (size_t)row * 128 + q * 8 + 4) = z;
        }
        return;
    }
    float acc[8];
    #pragma unroll
    for (int k = 0; k < 8; ++k) acc[k] = 0.f;
    int trips = (end - beg + 3) >> 2;
    #pragma unroll 4
    for (int t = 0; t < trips; ++t) {
        int idx = beg + t * 4 + g;
        bool valid = idx < end;
        int2 p = ep[valid ? idx : end - 1];
        float wv = valid ? __int_as_float(p.y) : 0.f;
        uint4 v = x4[(uint)p.x * 16u + q];
        acc[0] += wv * __uint_as_float(v.x << 16);
        acc[1] += wv * __uint_as_float(v.x & 0xffff0000u);
        acc[2] += wv * __uint_as_float(v.y << 16);
        acc[3] += wv * __uint_as_float(v.y & 0xffff0000u);
        acc[4] += wv * __uint_as_float(v.z << 16);
        acc[5] += wv * __uint_as_float(v.z & 0xffff0000u);
        acc[6] += wv * __uint_as_float(v.w << 16);
        acc[7] += wv * __uint_as_float(v.w & 0xffff0000u);
    }
    #pragma unroll
    for (int k = 0; k < 8; ++k) {
        acc[k] += __shfl_xor(acc[k], 16);
        acc[k] += __shfl_xor(acc[k], 32);
    }
    if (lane < 16) {
        float4 a = {acc[0], acc[1], acc[2], acc[3]};
        float4 b = {acc[4], acc[5], acc[6], acc[7]};
        *reinterpret_cast<float4*>(out + (size_t)row * 128 + q * 8) = a;
        *reinterpret_cast<float4*>(out + (size_t)row * 128 + q * 8 + 4) = b;
    }
}

// spmm_g: row = 64 bf16 = 128B = 8 lanes x uint4 -> 8 edges per wave-instruction.
__global__ void spmm_g_bf16(const int2* __restrict__ ep, const int* __restrict__ rp,
                            const uint4* __restrict__ g4 /* [N][8] */,
                            const float* __restrict__ bias, float* __restrict__ out, int n) {
    int row = blockIdx.x * 4 + (threadIdx.x >> 6);
    if (row >= n) return;
    int lane = threadIdx.x & 63;
    int g = lane >> 3;  // edge-group 0..7
    int q = lane & 7;   // 16B chunk within row
    float4 bv0 = *reinterpret_cast<const float4*>(bias + q * 8);
    float4 bv1 = *reinterpret_cast<const float4*>(bias + q * 8 + 4);
    int beg = rp[row], end = rp[row + 1];
    if (end <= beg) {
        if (lane < 8) {
            *reinterpret_cast<float4*>(out + (size_t)row * 64 + q * 8) = bv0;
            *reinterpret_cast<float4*>(out + (size_t)row * 64 + q * 8 + 4) = bv1;
        }
        return;
    }
    float acc[8];
    #pragma unroll
    for (int k = 0; k < 8; ++k) acc[k] = 0.f;
    int trips = (end - beg + 7) >> 3;
    #pragma unroll 4
    for (int t = 0; t < trips; ++t) {
        int idx = beg + t * 8 + g;
        bool valid = idx < end;
        int2 p = ep[valid ? idx : end - 1];
        float wv = valid ? __int_as_float(p.y) : 0.f;
        uint4 v = g4[(uint)p.x * 8u + q];
        acc[0] += wv * __uint_as_float(v.x << 16);
        acc[1] += wv * __uint_as_float(v.x & 0xffff0000u);
        acc[2] += wv * __uint_as_float(v.y << 16);
        acc[3] += wv * __uint_as_float(v.y & 0xffff0000u);
        acc[4] += wv * __uint_as_float(v.z << 16);
        acc[5] += wv * __uint_as_float(v.z & 0xffff0000u);
        acc[6] += wv * __uint_as_float(v.w << 16);
        acc[7] += wv * __uint_as_float(v.w & 0xffff0000u);
    }
    #pragma unroll
    for (int k = 0; k < 8; ++k) {
        acc[k] += __shfl_xor(acc[k], 8);
        acc[k] += __shfl_xor(acc[k], 16);
        acc[k] += __shfl_xor(acc[k], 32);
    }
    if (lane < 8) {
        float4 a = {acc[0] + bv0.x, acc[1] + bv0.y, acc[2] + bv0.z, acc[3] + bv0.w};
        float4 b = {acc[4] + bv1.x, acc[5] + bv1.y, acc[6] + bv1.z, acc[7] + bv1.w};
        *reinterpret_cast<float4*>(out + (size_t)row * 64 + q * 8) = a;
        *reinterpret_cast<float4*>(out + (size_t)row * 64 + q * 8 + 4) = b;
    }
}

// ---------------- dense GEMMs (f32 vector ALU; no fp32 MFMA on CDNA4) ----------------

// s[N,128] @ W1[128,256] + b1, relu -> h[N,256].  32 rows/block, 256 threads.
__global__ void gemm1_kernel(const float* __restrict__ A, const float* __restrict__ W,
                             const float* __restrict__ bias, float* __restrict__ out) {
    __shared__ float4 tile[32][32];  // 32 rows x 128 k  (16 KiB)
    int tx = threadIdx.x;
    int row0 = blockIdx.x * 32;
    #pragma unroll
    for (int i = 0; i < 4; ++i) {
        int idx = i * 256 + tx;
        int r = idx >> 5, c = idx & 31;
        tile[r][c] = *reinterpret_cast<const float4*>(A + (size_t)(row0 + r) * 128 + c * 4);
    }
    __syncthreads();
    int w = tx >> 6;   // wave -> rows w*8..w*8+7
    int l = tx & 63;   // cols 4l..4l+3
    float4 acc[8];
    #pragma unroll
    for (int r = 0; r < 8; ++r) { acc[r].x = acc[r].y = acc[r].z = acc[r].w = 0.f; }
    for (int k4 = 0; k4 < 32; ++k4) {
        float4 wv0 = *reinterpret_cast<const float4*>(W + (size_t)(k4 * 4 + 0) * 256 + l * 4);
        float4 wv1 = *reinterpret_cast<const float4*>(W + (size_t)(k4 * 4 + 1) * 256 + l * 4);
        float4 wv2 = *reinterpret_cast<const float4*>(W + (size_t)(k4 * 4 + 2) * 256 + l * 4);
        float4 wv3 = *reinterpret_cast<const float4*>(W + (size_t)(k4 * 4 + 3) * 256 + l * 4);
        #pragma unroll
        for (int r = 0; r < 8; ++r) {
            float4 a = tile[w * 8 + r][k4];  // wave-uniform -> LDS broadcast
            acc[r].x += a.x * wv0.x + a.y * wv1.x + a.z * wv2.x + a.w * wv3.x;
            acc[r].y += a.x * wv0.y + a.y * wv1.y + a.z * wv2.y + a.w * wv3.y;
            acc[r].z += a.x * wv0.z + a.y * wv1.z + a.z * wv2.z + a.w * wv3.z;
            acc[r].w += a.x * wv0.w + a.y * wv1.w + a.z * wv2.w + a.w * wv3.w;
        }
    }
    float4 bv = *reinterpret_cast<const float4*>(bias + l * 4);
    #pragma unroll
    for (int r = 0; r < 8; ++r) {
        float4 v;
        v.x = fmaxf(acc[r].x + bv.x, 0.f);
        v.y = fmaxf(acc[r].y + bv.y, 0.f);
        v.z = fmaxf(acc[r].z + bv.z, 0.f);
        v.w = fmaxf(acc[r].w + bv.w, 0.f);
        *reinterpret_cast<float4*>(out + (size_t)(row0 + w * 8 + r) * 256 + l * 4) = v;
    }
}

// h[N,256] @ W2[256,64] -> g[N,64] in bf16.  32 rows/block, 256 threads.
__global__ void gemm2_kernel(const float* __restrict__ A, const float* __restrict__ W,
                             ushort* __restrict__ out) {
    __shared__ float4 tile[32][65];  // 32 rows x 256 k, padded
    int tx = threadIdx.x;
    int row0 = blockIdx.x * 32;
    #pragma unroll
    for (int i = 0; i < 8; ++i) {
        int idx = i * 256 + tx;
        int r = idx >> 6, c = idx & 63;
        tile[r][c] = *reinterpret_cast<const float4*>(A + (size_t)(row0 + r) * 256 + c * 4);
    }
    __syncthreads();
    int w = tx >> 6;
    int l = tx & 63;
    int cg = (l & 15) * 4;  // cols cg..cg+3
    int s = l >> 4;         // row-sub 0..3
    int rbase = w * 8 + s * 2;
    float4 acc[2];
    #pragma unroll
    for (int r = 0; r < 2; ++r) { acc[r].x = acc[r].y = acc[r].z = acc[r].w = 0.f; }
    for (int k4 = 0; k4 < 64; ++k4) {
        float4 wv0 = *reinterpret_cast<const float4*>(W + (size_t)(k4 * 4 + 0) * 64 + cg);
        float4 wv1 = *reinterpret_cast<const float4*>(W + (size_t)(k4 * 4 + 1) * 64 + cg);
        float4 wv2 = *reinterpret_cast<const float4*>(W + (size_t)(k4 * 4 + 2) * 64 + cg);
        float4 wv3 = *reinterpret_cast<const float4*>(W + (size_t)(k4 * 4 + 3) * 64 + cg);
        #pragma unroll
        for (int r = 0; r < 2; ++r) {
            float4 a = tile[rbase + r][k4];
            acc[r].x += a.x * wv0.x + a.y * wv1.x + a.z * wv2.x + a.w * wv3.x;
            acc[r].y += a.x * wv0.y + a.y * wv1.y + a.z * wv2.y + a.w * wv3.y;
            acc[r].z += a.x * wv0.z + a.y * wv1.z + a.z * wv2.z + a.w * wv3.z;
            acc[r].w += a.x * wv0.w + a.y * wv1.w + a.z * wv2.w + a.w * wv3.w;
        }
    }
    #pragma unroll
    for (int r = 0; r < 2; ++r) {
        ushort4 o;
        o.x = f2bf(acc[r].x); o.y = f2bf(acc[r].y);
        o.z = f2bf(acc[r].z); o.w = f2bf(acc[r].w);
        *reinterpret_cast<ushort4*>(out + (size_t)(row0 + rbase + r) * 64 + cg) = o;
    }
}

// ---------------- launch ----------------

extern "C" void kernel_launch(void* const* d_in, const int* in_sizes, int n_in,
                              void* d_out, int out_size, void* d_ws, size_t ws_size,
                              hipStream_t stream) {
    const float* x     = (const float*)d_in[0];
    const int*   ei    = (const int*)d_in[1];
    const float* ew_in = (const float*)d_in[2];
    const float* W1    = (const float*)d_in[3];
    const float* b1    = (const float*)d_in[4];
    const float* W2    = (const float*)d_in[5];
    const float* b2    = (const float*)d_in[6];
    float* outp = (float*)d_out;

    const int n = N_NODES, e = N_EDGES;
    const int* dst = ei;       // edge_index[0]
    const int* src = ei + e;   // edge_index[1]

    char* ws = (char*)d_ws;
    size_t off = 0;
    auto alloc = [&](size_t bytes) {
        void* p = ws + off;
        off += (bytes + 255) & ~size_t(255);
        return p;
    };
    int2*  ep   = (int2*)alloc(sizeof(int2) * (size_t)e);
    int*   cnt  = (int*)alloc(sizeof(int) * (size_t)n * 2);  // cnt + fill
    int*   fill = cnt + n;
    int*   rp   = (int*)alloc(sizeof(int) * (size_t)(n + 1));
    int*   bsum = (int*)alloc(sizeof(int) * 256);
    float* sbuf = (float*)alloc(sizeof(float) * (size_t)n * 128);
    float* hbuf = (float*)alloc(sizeof(float) * (size_t)n * 256);
    ushort* x2  = (ushort*)hbuf;  // x-bf16 lives in hbuf region; dead before gemm1 writes h
    ushort* g2  = (ushort*)sbuf;  // g-bf16 reuses sbuf (s dead after gemm1)

    const int nb = (n + 1023) / 1024;  // 98

    hipMemsetAsync(cnt, 0, sizeof(int) * (size_t)n * 2, stream);
    cast_bf16_kernel<<<(n * 128 / 8 + 255) / 256, 256, 0, stream>>>(x, x2, n * 128 / 8);
    hist_kernel<<<(e + 255) / 256, 256, 0, stream>>>(dst, cnt, e);
    scan1_kernel<<<nb, 1024, 0, stream>>>(cnt, rp, bsum, n);
    scan2_kernel<<<1, 128, 0, stream>>>(bsum, rp, nb, n);
    scan3_kernel<<<nb, 1024, 0, stream>>>(rp, bsum, n);
    scatter_kernel<<<(e + 255) / 256, 256, 0, stream>>>(dst, src, ew_in, e, rp, fill, ep);

    // layer 1 (restructured): s = A @ x ; h = relu(s @ W1 + b1)
    spmm_x_bf16<<<(n + 3) / 4, 256, 0, stream>>>(ep, rp, (const uint4*)x2, sbuf, n);
    gemm1_kernel<<<n / 32, 256, 0, stream>>>(sbuf, W1, b1, hbuf);

    // layer 2: g = h @ W2 (bf16) ; out = A @ g + b2
    gemm2_kernel<<<n / 32, 256, 0, stream>>>(hbuf, W2, g2);
    spmm_g_bf16<<<(n + 3) / 4, 256, 0, stream>>>(ep, rp, (const uint4*)g2, b2, outp, n);
}

// Round 5
// 470.814 us; speedup vs baseline: 1.8385x; 1.4452x over previous
//
#include <hip/hip_runtime.h>

#define NN 100000
#define NE 3200000
#define SH 9                 // bucket = dst >> 9  (512 nodes/bucket)
#define BW 512               // 1 << SH
#define NBUK 196             // ceil(NN / BW)
#define P1_BLOCKS 250
#define P1_CHUNK 12800       // 250 * 12800 == NE exactly
#define P2_CAP 18000         // max edges/bucket (mean 16327, sd ~127 -> +13 sigma)

__device__ inline ushort f2bf(float f) {  // RNE f32 -> bf16
    uint u = __float_as_uint(f);
    return (ushort)((u + 0x7fffu + ((u >> 16) & 1u)) >> 16);
}

// ---------------- CSR build: bucket histogram + scan ----------------

__global__ void bcount_kernel(const int* __restrict__ dst, int* __restrict__ bcnt) {
    __shared__ int c[NBUK];
    int tx = threadIdx.x;
    for (int i = tx; i < NBUK; i += 512) c[i] = 0;
    __syncthreads();
    int i0 = blockIdx.x * P1_CHUNK;
    for (int i = i0 + tx; i < i0 + P1_CHUNK; i += 512) atomicAdd(&c[dst[i] >> SH], 1);
    __syncthreads();
    for (int i = tx; i < NBUK; i += 512) if (c[i]) atomicAdd(&bcnt[i], c[i]);
}

__global__ void bscan_kernel(const int* __restrict__ bcnt, int* __restrict__ bstart,
                             int* __restrict__ gtail, int* __restrict__ rp) {
    __shared__ int t[256];
    int tx = threadIdx.x;
    int v = (tx < NBUK) ? bcnt[tx] : 0;
    t[tx] = v;
    __syncthreads();
    #pragma unroll
    for (int off = 1; off < 256; off <<= 1) {
        int u = (tx >= off) ? t[tx - off] : 0;
        __syncthreads();
        t[tx] += u;
        __syncthreads();
    }
    if (tx < NBUK) { bstart[tx] = t[tx] - v; gtail[tx] = t[tx] - v; }
    if (tx == NBUK - 1) bstart[NBUK] = t[tx];
    if (tx == 0) rp[NN] = NE;
}

// ---------------- part1: bucket-scatter with LDS reorder ----------------
// record: x = src(bits 0-16) | dstLow(bits 17-25), y = f32 weight bits

__global__ __launch_bounds__(512, 1) void part1_kernel(
        const int* __restrict__ dst, const int* __restrict__ src,
        const float* __restrict__ w, int* __restrict__ gtail, uint2* __restrict__ stg) {
    __shared__ uint2 rec[P1_CHUNK];           // 102400 B
    __shared__ unsigned char map[P1_CHUNK];   // 12800 B (slot -> bucket)
    __shared__ int cnt[NBUK], gbase[NBUK], lbase[NBUK], sc[256];
    int tx = threadIdx.x;
    int i0 = blockIdx.x * P1_CHUNK;

    for (int i = tx; i < NBUK; i += 512) cnt[i] = 0;
    __syncthreads();
    for (int i = i0 + tx; i < i0 + P1_CHUNK; i += 512) atomicAdd(&cnt[dst[i] >> SH], 1);
    __syncthreads();
    // reserve global space per bucket
    if (tx < NBUK) gbase[tx] = atomicAdd(&gtail[tx], cnt[tx]);
    // exclusive scan of cnt -> lbase
    if (tx < 256) sc[tx] = (tx < NBUK) ? cnt[tx] : 0;
    __syncthreads();
    int sv = (tx < 256) ? sc[tx] : 0;
    #pragma unroll
    for (int off = 1; off < 256; off <<= 1) {
        int u = (tx < 256 && tx >= off) ? sc[tx - off] : 0;
        __syncthreads();
        if (tx < 256) sc[tx] += u;
        __syncthreads();
    }
    if (tx < NBUK) lbase[tx] = sc[tx] - sv;
    __syncthreads();
    // slot -> bucket map (wave-cooperative per-bucket segments)
    {
        int wv = tx >> 6, ln = tx & 63;
        for (int b = wv; b < NBUK; b += 8) {
            int s0 = lbase[b], c = cnt[b];
            for (int s = ln; s < c; s += 64) map[s0 + s] = (unsigned char)b;
        }
    }
    __syncthreads();
    for (int i = tx; i < NBUK; i += 512) cnt[i] = 0;  // reuse as fill
    __syncthreads();
    // LDS scatter into bucket order
    for (int i = i0 + tx; i < i0 + P1_CHUNK; i += 512) {
        int d = dst[i];
        int b = d >> SH;
        int r = atomicAdd(&cnt[b], 1);
        rec[lbase[b] + r] = make_uint2((uint)src[i] | ((uint)(d & (BW - 1)) << 17),
                                       (uint)__float_as_int(w[i]));
    }
    __syncthreads();
    // coalesced write-out (runs of ~65 edges per bucket are contiguous)
    for (int s = tx; s < P1_CHUNK; s += 512) {
        int b = map[s];
        stg[gbase[b] + (s - lbase[b])] = rec[s];
    }
}

// ---------------- part2: per-bucket dst-sort, rp write, linear ep write ----------------

__global__ __launch_bounds__(512, 1) void part2_kernel(
        const uint2* __restrict__ stg, const int* __restrict__ bstart,
        int* __restrict__ rp, int2* __restrict__ ep) {
    __shared__ uint2 st[P2_CAP];   // 144000 B
    __shared__ int cnt[512], lbase[512];
    int tx = threadIdx.x;
    int b = blockIdx.x;
    int s0 = bstart[b], s1 = bstart[b + 1];
    int len = s1 - s0;
    cnt[tx] = 0;
    __syncthreads();
    for (int i = tx; i < len; i += 512) atomicAdd(&cnt[stg[s0 + i].x >> 17], 1);
    __syncthreads();
    int v = cnt[tx];
    #pragma unroll
    for (int off = 1; off < 512; off <<= 1) {
        int u = (tx >= off) ? cnt[tx - off] : 0;
        __syncthreads();
        cnt[tx] += u;
        __syncthreads();
    }
    lbase[tx] = cnt[tx] - v;  // exclusive
    int node = (b << SH) + tx;
    if (node < NN) rp[node] = s0 + lbase[tx];
    __syncthreads();
    cnt[tx] = 0;  // reuse as fill
    __syncthreads();
    for (int i = tx; i < len; i += 512) {
        uint2 p = stg[s0 + i];
        int dl = p.x >> 17;
        int r = atomicAdd(&cnt[dl], 1);
        st[lbase[dl] + r] = make_uint2(p.x & 0x1FFFFu, p.y);
    }
    __syncthreads();
    for (int i = tx; i < len; i += 512) {
        uint2 q = st[i];
        ep[s0 + i] = make_int2((int)q.x, (int)q.y);
    }
}

// ---------------- cast x -> bf16 ----------------

__global__ void cast_bf16_kernel(const float* __restrict__ in, ushort* __restrict__ out, int n8) {
    int i = blockIdx.x * blockDim.x + threadIdx.x;
    if (i >= n8) return;
    size_t base = (size_t)i * 8;
    float4 a = *reinterpret_cast<const float4*>(in + base);
    float4 b = *reinterpret_cast<const float4*>(in + base + 4);
    ushort4 o0, o1;
    o0.x = f2bf(a.x); o0.y = f2bf(a.y); o0.z = f2bf(a.z); o0.w = f2bf(a.w);
    o1.x = f2bf(b.x); o1.y = f2bf(b.y); o1.z = f2bf(b.z); o1.w = f2bf(b.w);
    *reinterpret_cast<ushort4*>(out + base) = o0;
    *reinterpret_cast<ushort4*>(out + base + 4) = o1;
}

// ---------------- CSR SpMM (wide bf16 gathers, group-per-edge) ----------------

__global__ void spmm_x_bf16(const int2* __restrict__ ep, const int* __restrict__ rp,
                            const uint4* __restrict__ x4 /* [N][16] */,
                            float* __restrict__ out, int n) {
    int row = blockIdx.x * 4 + (threadIdx.x >> 6);
    if (row >= n) return;
    int lane = threadIdx.x & 63;
    int g = lane >> 4;   // edge-group 0..3
    int q = lane & 15;   // 16B chunk within row
    int beg = rp[row], end = rp[row + 1];
    if (end <= beg) {
        if (lane < 16) {
            float4 z = {0.f, 0.f, 0.f, 0.f};
            *reinterpret_cast<float4*>(out + (size_t)row * 128 + q * 8) = z;
            *reinterpret_cast<float4*>(out + (size_t)row * 128 + q * 8 + 4) = z;
        }
        return;
    }
    float acc[8];
    #pragma unroll
    for (int k = 0; k < 8; ++k) acc[k] = 0.f;
    int trips = (end - beg + 3) >> 2;
    #pragma unroll 4
    for (int t = 0; t < trips; ++t) {
        int idx = beg + t * 4 + g;
        bool valid = idx < end;
        int2 p = ep[valid ? idx : end - 1];
        float wv = valid ? __int_as_float(p.y) : 0.f;
        uint4 v = x4[(uint)p.x * 16u + q];
        acc[0] += wv * __uint_as_float(v.x << 16);
        acc[1] += wv * __uint_as_float(v.x & 0xffff0000u);
        acc[2] += wv * __uint_as_float(v.y << 16);
        acc[3] += wv * __uint_as_float(v.y & 0xffff0000u);
        acc[4] += wv * __uint_as_float(v.z << 16);
        acc[5] += wv * __uint_as_float(v.z & 0xffff0000u);
        acc[6] += wv * __uint_as_float(v.w << 16);
        acc[7] += wv * __uint_as_float(v.w & 0xffff0000u);
    }
    #pragma unroll
    for (int k = 0; k < 8; ++k) {
        acc[k] += __shfl_xor(acc[k], 16);
        acc[k] += __shfl_xor(acc[k], 32);
    }
    if (lane < 16) {
        float4 a = {acc[0], acc[1], acc[2], acc[3]};
        float4 b = {acc[4], acc[5], acc[6], acc[7]};
        *reinterpret_cast<float4*>(out + (size_t)row * 128 + q * 8) = a;
        *reinterpret_cast<float4*>(out + (size_t)row * 128 + q * 8 + 4) = b;
    }
}

__global__ void spmm_g_bf16(const int2* __restrict__ ep, const int* __restrict__ rp,
                            const uint4* __restrict__ g4 /* [N][8] */,
                            const float* __restrict__ bias, float* __restrict__ out, int n) {
    int row = blockIdx.x * 4 + (threadIdx.x >> 6);
    if (row >= n) return;
    int lane = threadIdx.x & 63;
    int g = lane >> 3;  // edge-group 0..7
    int q = lane & 7;   // 16B chunk within row
    float4 bv0 = *reinterpret_cast<const float4*>(bias + q * 8);
    float4 bv1 = *reinterpret_cast<const float4*>(bias + q * 8 + 4);
    int beg = rp[row], end = rp[row + 1];
    if (end <= beg) {
        if (lane < 8) {
            *reinterpret_cast<float4*>(out + (size_t)row * 64 + q * 8) = bv0;
            *reinterpret_cast<float4*>(out + (size_t)row * 64 + q * 8 + 4) = bv1;
        }
        return;
    }
    float acc[8];
    #pragma unroll
    for (int k = 0; k < 8; ++k) acc[k] = 0.f;
    int trips = (end - beg + 7) >> 3;
    #pragma unroll 4
    for (int t = 0; t < trips; ++t) {
        int idx = beg + t * 8 + g;
        bool valid = idx < end;
        int2 p = ep[valid ? idx : end - 1];
        float wv = valid ? __int_as_float(p.y) : 0.f;
        uint4 v = g4[(uint)p.x * 8u + q];
        acc[0] += wv * __uint_as_float(v.x << 16);
        acc[1] += wv * __uint_as_float(v.x & 0xffff0000u);
        acc[2] += wv * __uint_as_float(v.y << 16);
        acc[3] += wv * __uint_as_float(v.y & 0xffff0000u);
        acc[4] += wv * __uint_as_float(v.z << 16);
        acc[5] += wv * __uint_as_float(v.z & 0xffff0000u);
        acc[6] += wv * __uint_as_float(v.w << 16);
        acc[7] += wv * __uint_as_float(v.w & 0xffff0000u);
    }
    #pragma unroll
    for (int k = 0; k < 8; ++k) {
        acc[k] += __shfl_xor(acc[k], 8);
        acc[k] += __shfl_xor(acc[k], 16);
        acc[k] += __shfl_xor(acc[k], 32);
    }
    if (lane < 8) {
        float4 a = {acc[0] + bv0.x, acc[1] + bv0.y, acc[2] + bv0.z, acc[3] + bv0.w};
        float4 b = {acc[4] + bv1.x, acc[5] + bv1.y, acc[6] + bv1.z, acc[7] + bv1.w};
        *reinterpret_cast<float4*>(out + (size_t)row * 64 + q * 8) = a;
        *reinterpret_cast<float4*>(out + (size_t)row * 64 + q * 8 + 4) = b;
    }
}

// ---------------- dense GEMMs (f32 vector ALU; no fp32 MFMA on CDNA4) ----------------

__global__ void gemm1_kernel(const float* __restrict__ A, const float* __restrict__ W,
                             const float* __restrict__ bias, float* __restrict__ out) {
    __shared__ float4 tile[32][32];
    int tx = threadIdx.x;
    int row0 = blockIdx.x * 32;
    #pragma unroll
    for (int i = 0; i < 4; ++i) {
        int idx = i * 256 + tx;
        int r = idx >> 5, c = idx & 31;
        tile[r][c] = *reinterpret_cast<const float4*>(A + (size_t)(row0 + r) * 128 + c * 4);
    }
    __syncthreads();
    int w = tx >> 6;
    int l = tx & 63;
    float4 acc[8];
    #pragma unroll
    for (int r = 0; r < 8; ++r) { acc[r].x = acc[r].y = acc[r].z = acc[r].w = 0.f; }
    for (int k4 = 0; k4 < 32; ++k4) {
        float4 wv0 = *reinterpret_cast<const float4*>(W + (size_t)(k4 * 4 + 0) * 256 + l * 4);
        float4 wv1 = *reinterpret_cast<const float4*>(W + (size_t)(k4 * 4 + 1) * 256 + l * 4);
        float4 wv2 = *reinterpret_cast<const float4*>(W + (size_t)(k4 * 4 + 2) * 256 + l * 4);
        float4 wv3 = *reinterpret_cast<const float4*>(W + (size_t)(k4 * 4 + 3) * 256 + l * 4);
        #pragma unroll
        for (int r = 0; r < 8; ++r) {
            float4 a = tile[w * 8 + r][k4];
            acc[r].x += a.x * wv0.x + a.y * wv1.x + a.z * wv2.x + a.w * wv3.x;
            acc[r].y += a.x * wv0.y + a.y * wv1.y + a.z * wv2.y + a.w * wv3.y;
            acc[r].z += a.x * wv0.z + a.y * wv1.z + a.z * wv2.z + a.w * wv3.z;
            acc[r].w += a.x * wv0.w + a.y * wv1.w + a.z * wv2.w + a.w * wv3.w;
        }
    }
    float4 bv = *reinterpret_cast<const float4*>(bias + l * 4);
    #pragma unroll
    for (int r = 0; r < 8; ++r) {
        float4 v;
        v.x = fmaxf(acc[r].x + bv.x, 0.f);
        v.y = fmaxf(acc[r].y + bv.y, 0.f);
        v.z = fmaxf(acc[r].z + bv.z, 0.f);
        v.w = fmaxf(acc[r].w + bv.w, 0.f);
        *reinterpret_cast<float4*>(out + (size_t)(row0 + w * 8 + r) * 256 + l * 4) = v;
    }
}

__global__ void gemm2_kernel(const float* __restrict__ A, const float* __restrict__ W,
                             ushort* __restrict__ out) {
    __shared__ float4 tile[32][65];
    int tx = threadIdx.x;
    int row0 = blockIdx.x * 32;
    #pragma unroll
    for (int i = 0; i < 8; ++i) {
        int idx = i * 256 + tx;
        int r = idx >> 6, c = idx & 63;
        tile[r][c] = *reinterpret_cast<const float4*>(A + (size_t)(row0 + r) * 256 + c * 4);
    }
    __syncthreads();
    int w = tx >> 6;
    int l = tx & 63;
    int cg = (l & 15) * 4;
    int s = l >> 4;
    int rbase = w * 8 + s * 2;
    float4 acc[2];
    #pragma unroll
    for (int r = 0; r < 2; ++r) { acc[r].x = acc[r].y = acc[r].z = acc[r].w = 0.f; }
    for (int k4 = 0; k4 < 64; ++k4) {
        float4 wv0 = *reinterpret_cast<const float4*>(W + (size_t)(k4 * 4 + 0) * 64 + cg);
        float4 wv1 = *reinterpret_cast<const float4*>(W + (size_t)(k4 * 4 + 1) * 64 + cg);
        float4 wv2 = *reinterpret_cast<const float4*>(W + (size_t)(k4 * 4 + 2) * 64 + cg);
        float4 wv3 = *reinterpret_cast<const float4*>(W + (size_t)(k4 * 4 + 3) * 64 + cg);
        #pragma unroll
        for (int r = 0; r < 2; ++r) {
            float4 a = tile[rbase + r][k4];
            acc[r].x += a.x * wv0.x + a.y * wv1.x + a.z * wv2.x + a.w * wv3.x;
            acc[r].y += a.x * wv0.y + a.y * wv1.y + a.z * wv2.y + a.w * wv3.y;
            acc[r].z += a.x * wv0.z + a.y * wv1.z + a.z * wv2.z + a.w * wv3.z;
            acc[r].w += a.x * wv0.w + a.y * wv1.w + a.z * wv2.w + a.w * wv3.w;
        }
    }
    #pragma unroll
    for (int r = 0; r < 2; ++r) {
        ushort4 o;
        o.x = f2bf(acc[r].x); o.y = f2bf(acc[r].y);
        o.z = f2bf(acc[r].z); o.w = f2bf(acc[r].w);
        *reinterpret_cast<ushort4*>(out + (size_t)(row0 + rbase + r) * 64 + cg) = o;
    }
}

// ---------------- launch ----------------

extern "C" void kernel_launch(void* const* d_in, const int* in_sizes, int n_in,
                              void* d_out, int out_size, void* d_ws, size_t ws_size,
                              hipStream_t stream) {
    const float* x     = (const float*)d_in[0];
    const int*   ei    = (const int*)d_in[1];
    const float* ew_in = (const float*)d_in[2];
    const float* W1    = (const float*)d_in[3];
    const float* b1    = (const float*)d_in[4];
    const float* W2    = (const float*)d_in[5];
    const float* b2    = (const float*)d_in[6];
    float* outp = (float*)d_out;

    const int n = NN, e = NE;
    const int* dst = ei;       // edge_index[0]
    const int* src = ei + e;   // edge_index[1]

    char* ws = (char*)d_ws;
    size_t off = 0;
    auto alloc = [&](size_t bytes) {
        void* p = ws + off;
        off += (bytes + 255) & ~size_t(255);
        return p;
    };
    int2*  ep     = (int2*)alloc(sizeof(int2) * (size_t)e);
    int*   bcnt   = (int*)alloc(sizeof(int) * NBUK);
    int*   bstart = (int*)alloc(sizeof(int) * (NBUK + 1));
    int*   gtail  = (int*)alloc(sizeof(int) * NBUK);
    int*   rp     = (int*)alloc(sizeof(int) * (size_t)(n + 1));
    float* sbuf   = (float*)alloc(sizeof(float) * (size_t)n * 128);
    float* hbuf   = (float*)alloc(sizeof(float) * (size_t)n * 256);
    // aliases inside hbuf (dead until gemm1 writes h):
    ushort* x2 = (ushort*)hbuf;                                   // [0, 25.6MB): bf16 x
    uint2*  stg = (uint2*)((char*)hbuf + (size_t)n * 128 * 2);    // [25.6, 51.2MB): staging
    ushort* g2  = (ushort*)sbuf;  // g-bf16 reuses sbuf (s dead after gemm1)

    hipMemsetAsync(bcnt, 0, sizeof(int) * NBUK, stream);
    bcount_kernel<<<P1_BLOCKS, 512, 0, stream>>>(dst, bcnt);
    bscan_kernel<<<1, 256, 0, stream>>>(bcnt, bstart, gtail, rp);
    cast_bf16_kernel<<<(n * 128 / 8 + 255) / 256, 256, 0, stream>>>(x, x2, n * 128 / 8);
    part1_kernel<<<P1_BLOCKS, 512, 0, stream>>>(dst, src, ew_in, gtail, stg);
    part2_kernel<<<NBUK, 512, 0, stream>>>(stg, bstart, rp, ep);

    // layer 1 (restructured): s = A @ x ; h = relu(s @ W1 + b1)
    spmm_x_bf16<<<(n + 3) / 4, 256, 0, stream>>>(ep, rp, (const uint4*)x2, sbuf, n);
    gemm1_kernel<<<n / 32, 256, 0, stream>>>(sbuf, W1, b1, hbuf);

    // layer 2: g = h @ W2 (bf16) ; out = A @ g + b2
    gemm2_kernel<<<n / 32, 256, 0, stream>>>(hbuf, W2, g2);
    spmm_g_bf16<<<(n + 3) / 4, 256, 0, stream>>>(ep, rp, (const uint4*)g2, b2, outp, n);
}

// Round 6
// 340.405 us; speedup vs baseline: 2.5428x; 1.3831x over previous
//
#include <hip/hip_runtime.h>

#define NN 100000
#define NE 3200000
#define SH 9                 // bucket = dst >> 9  (512 nodes/bucket)
#define BW 512               // 1 << SH
#define NBUK 196             // ceil(NN / BW)
#define P1_BLOCKS 250
#define P1_CHUNK 12800       // 250 * 12800 == NE exactly
#define P2_CAP 18000         // max edges/bucket (mean 16327, sd ~127)

using bf16x8 = __attribute__((ext_vector_type(8))) short;
using f32x4  = __attribute__((ext_vector_type(4))) float;

__device__ inline ushort f2bf(float f) {  // RNE f32 -> bf16
    uint u = __float_as_uint(f);
    return (ushort)((u + 0x7fffu + ((u >> 16) & 1u)) >> 16);
}
__device__ inline uint pk2bf(float a, float b) {
    return (uint)f2bf(a) | ((uint)f2bf(b) << 16);
}

// ---------------- CSR build: bucket histogram + scan ----------------

__global__ void bcount_kernel(const int* __restrict__ dst, int* __restrict__ bcnt) {
    __shared__ int c[NBUK];
    int tx = threadIdx.x;
    for (int i = tx; i < NBUK; i += 512) c[i] = 0;
    __syncthreads();
    int i0 = blockIdx.x * P1_CHUNK;
    for (int i = i0 + tx; i < i0 + P1_CHUNK; i += 512) atomicAdd(&c[dst[i] >> SH], 1);
    __syncthreads();
    for (int i = tx; i < NBUK; i += 512) if (c[i]) atomicAdd(&bcnt[i], c[i]);
}

__global__ void bscan_kernel(const int* __restrict__ bcnt, int* __restrict__ bstart,
                             int* __restrict__ gtail, int* __restrict__ rp) {
    __shared__ int t[256];
    int tx = threadIdx.x;
    int v = (tx < NBUK) ? bcnt[tx] : 0;
    t[tx] = v;
    __syncthreads();
    #pragma unroll
    for (int off = 1; off < 256; off <<= 1) {
        int u = (tx >= off) ? t[tx - off] : 0;
        __syncthreads();
        t[tx] += u;
        __syncthreads();
    }
    if (tx < NBUK) { bstart[tx] = t[tx] - v; gtail[tx] = t[tx] - v; }
    if (tx == NBUK - 1) bstart[NBUK] = t[tx];
    if (tx == 0) rp[NN] = NE;
}

// ---------------- part1: bucket-scatter with LDS reorder ----------------

__global__ __launch_bounds__(512, 1) void part1_kernel(
        const int* __restrict__ dst, const int* __restrict__ src,
        const float* __restrict__ w, int* __restrict__ gtail, uint2* __restrict__ stg) {
    __shared__ uint2 rec[P1_CHUNK];           // 102400 B
    __shared__ unsigned char map[P1_CHUNK];   // 12800 B
    __shared__ int cnt[NBUK], gbase[NBUK], lbase[NBUK], sc[256];
    int tx = threadIdx.x;
    int i0 = blockIdx.x * P1_CHUNK;

    for (int i = tx; i < NBUK; i += 512) cnt[i] = 0;
    __syncthreads();
    for (int i = i0 + tx; i < i0 + P1_CHUNK; i += 512) atomicAdd(&cnt[dst[i] >> SH], 1);
    __syncthreads();
    if (tx < NBUK) gbase[tx] = atomicAdd(&gtail[tx], cnt[tx]);
    if (tx < 256) sc[tx] = (tx < NBUK) ? cnt[tx] : 0;
    __syncthreads();
    int sv = (tx < 256) ? sc[tx] : 0;
    #pragma unroll
    for (int off = 1; off < 256; off <<= 1) {
        int u = (tx < 256 && tx >= off) ? sc[tx - off] : 0;
        __syncthreads();
        if (tx < 256) sc[tx] += u;
        __syncthreads();
    }
    if (tx < NBUK) lbase[tx] = sc[tx] - sv;
    __syncthreads();
    {
        int wv = tx >> 6, ln = tx & 63;
        for (int b = wv; b < NBUK; b += 8) {
            int s0 = lbase[b], c = cnt[b];
            for (int s = ln; s < c; s += 64) map[s0 + s] = (unsigned char)b;
        }
    }
    __syncthreads();
    for (int i = tx; i < NBUK; i += 512) cnt[i] = 0;
    __syncthreads();
    for (int i = i0 + tx; i < i0 + P1_CHUNK; i += 512) {
        int d = dst[i];
        int b = d >> SH;
        int r = atomicAdd(&cnt[b], 1);
        rec[lbase[b] + r] = make_uint2((uint)src[i] | ((uint)(d & (BW - 1)) << 17),
                                       (uint)__float_as_int(w[i]));
    }
    __syncthreads();
    for (int s = tx; s < P1_CHUNK; s += 512) {
        int b = map[s];
        stg[gbase[b] + (s - lbase[b])] = rec[s];
    }
}

// ---------------- part2: per-bucket dst-sort, rp write, linear ep write ----------------

__global__ __launch_bounds__(512, 1) void part2_kernel(
        const uint2* __restrict__ stg, const int* __restrict__ bstart,
        int* __restrict__ rp, int2* __restrict__ ep) {
    __shared__ uint2 st[P2_CAP];   // 144000 B
    __shared__ int cnt[512], lbase[512];
    int tx = threadIdx.x;
    int b = blockIdx.x;
    int s0 = bstart[b], s1 = bstart[b + 1];
    int len = s1 - s0;
    cnt[tx] = 0;
    __syncthreads();
    for (int i = tx; i < len; i += 512) atomicAdd(&cnt[stg[s0 + i].x >> 17], 1);
    __syncthreads();
    int v = cnt[tx];
    #pragma unroll
    for (int off = 1; off < 512; off <<= 1) {
        int u = (tx >= off) ? cnt[tx - off] : 0;
        __syncthreads();
        cnt[tx] += u;
        __syncthreads();
    }
    lbase[tx] = cnt[tx] - v;
    int node = (b << SH) + tx;
    if (node < NN) rp[node] = s0 + lbase[tx];
    __syncthreads();
    cnt[tx] = 0;
    __syncthreads();
    for (int i = tx; i < len; i += 512) {
        uint2 p = stg[s0 + i];
        int dl = p.x >> 17;
        int r = atomicAdd(&cnt[dl], 1);
        st[lbase[dl] + r] = make_uint2(p.x & 0x1FFFFu, p.y);
    }
    __syncthreads();
    for (int i = tx; i < len; i += 512) {
        uint2 q = st[i];
        ep[s0 + i] = make_int2((int)q.x, (int)q.y);
    }
}

// ---------------- cast x -> bf16 ----------------

__global__ void cast_bf16_kernel(const float* __restrict__ in, ushort* __restrict__ out, int n8) {
    int i = blockIdx.x * blockDim.x + threadIdx.x;
    if (i >= n8) return;
    size_t base = (size_t)i * 8;
    float4 a = *reinterpret_cast<const float4*>(in + base);
    float4 b = *reinterpret_cast<const float4*>(in + base + 4);
    ushort4 o0, o1;
    o0.x = f2bf(a.x); o0.y = f2bf(a.y); o0.z = f2bf(a.z); o0.w = f2bf(a.w);
    o1.x = f2bf(b.x); o1.y = f2bf(b.y); o1.z = f2bf(b.z); o1.w = f2bf(b.w);
    *reinterpret_cast<ushort4*>(out + base) = o0;
    *reinterpret_cast<ushort4*>(out + base + 4) = o1;
}

// ---------------- pack W1/W2 into bf16 MFMA-B-fragment order ----------------
// w1p[((t*4+kk)*64 + l)*8 + j] = W1[kk*32 + (l>>4)*8 + j][t*16 + (l&15)]   (t<16)
// w2p[((t*8+kk)*64 + l)*8 + j] = W2[kk*32 + (l>>4)*8 + j][t*16 + (l&15)]   (t<4)

__global__ void pack_w_kernel(const float* __restrict__ W1, const float* __restrict__ W2,
                              ushort* __restrict__ w1p, ushort* __restrict__ w2p) {
    int i = blockIdx.x * 256 + threadIdx.x;  // coalesced read side
    if (i < 32768) {  // W1: 128x256
        int n = i & 255, k = i >> 8;
        int kk = k >> 5, hi = (k >> 3) & 3, j = k & 7;
        int t = n >> 4, l = hi * 16 + (n & 15);
        w1p[(((t * 4 + kk) * 64 + l) << 3) + j] = f2bf(W1[i]);
    }
    if (i < 16384) {  // W2: 256x64
        int n = i & 63, k = i >> 6;
        int kk = k >> 5, hi = (k >> 3) & 3, j = k & 7;
        int t = n >> 4, l = hi * 16 + (n & 15);
        w2p[(((t * 8 + kk) * 64 + l) << 3) + j] = f2bf(W2[i]);
    }
}

// ---------------- CSR SpMM (wide bf16 gathers, group-per-edge) ----------------

// s2 output in bf16 now.
__global__ void spmm_x_bf16(const int2* __restrict__ ep, const int* __restrict__ rp,
                            const uint4* __restrict__ x4 /* [N][16] */,
                            uint4* __restrict__ s2 /* [N][16] bf16 */, int n) {
    int row = blockIdx.x * 4 + (threadIdx.x >> 6);
    if (row >= n) return;
    int lane = threadIdx.x & 63;
    int g = lane >> 4;   // edge-group 0..3
    int q = lane & 15;   // 16B chunk within row
    int beg = rp[row], end = rp[row + 1];
    if (end <= beg) {
        if (lane < 16) s2[(size_t)row * 16 + q] = make_uint4(0, 0, 0, 0);
        return;
    }
    float acc[8];
    #pragma unroll
    for (int k = 0; k < 8; ++k) acc[k] = 0.f;
    int trips = (end - beg + 3) >> 2;
    #pragma unroll 8
    for (int t = 0; t < trips; ++t) {
        int idx = beg + t * 4 + g;
        bool valid = idx < end;
        int2 p = ep[valid ? idx : end - 1];
        float wv = valid ? __int_as_float(p.y) : 0.f;
        uint4 v = x4[(uint)p.x * 16u + q];
        acc[0] += wv * __uint_as_float(v.x << 16);
        acc[1] += wv * __uint_as_float(v.x & 0xffff0000u);
        acc[2] += wv * __uint_as_float(v.y << 16);
        acc[3] += wv * __uint_as_float(v.y & 0xffff0000u);
        acc[4] += wv * __uint_as_float(v.z << 16);
        acc[5] += wv * __uint_as_float(v.z & 0xffff0000u);
        acc[6] += wv * __uint_as_float(v.w << 16);
        acc[7] += wv * __uint_as_float(v.w & 0xffff0000u);
    }
    #pragma unroll
    for (int k = 0; k < 8; ++k) {
        acc[k] += __shfl_xor(acc[k], 16);
        acc[k] += __shfl_xor(acc[k], 32);
    }
    if (lane < 16) {
        uint4 o;
        o.x = pk2bf(acc[0], acc[1]);
        o.y = pk2bf(acc[2], acc[3]);
        o.z = pk2bf(acc[4], acc[5]);
        o.w = pk2bf(acc[6], acc[7]);
        s2[(size_t)row * 16 + q] = o;
    }
}

__global__ void spmm_g_bf16(const int2* __restrict__ ep, const int* __restrict__ rp,
                            const uint4* __restrict__ g4 /* [N][8] */,
                            const float* __restrict__ bias, float* __restrict__ out, int n) {
    int row = blockIdx.x * 4 + (threadIdx.x >> 6);
    if (row >= n) return;
    int lane = threadIdx.x & 63;
    int g = lane >> 3;  // edge-group 0..7
    int q = lane & 7;   // 16B chunk within row
    float4 bv0 = *reinterpret_cast<const float4*>(bias + q * 8);
    float4 bv1 = *reinterpret_cast<const float4*>(bias + q * 8 + 4);
    int beg = rp[row], end = rp[row + 1];
    if (end <= beg) {
        if (lane < 8) {
            *reinterpret_cast<float4*>(out + (size_t)row * 64 + q * 8) = bv0;
            *reinterpret_cast<float4*>(out + (size_t)row * 64 + q * 8 + 4) = bv1;
        }
        return;
    }
    float acc[8];
    #pragma unroll
    for (int k = 0; k < 8; ++k) acc[k] = 0.f;
    int trips = (end - beg + 7) >> 3;
    #pragma unroll 8
    for (int t = 0; t < trips; ++t) {
        int idx = beg + t * 8 + g;
        bool valid = idx < end;
        int2 p = ep[valid ? idx : end - 1];
        float wv = valid ? __int_as_float(p.y) : 0.f;
        uint4 v = g4[(uint)p.x * 8u + q];
        acc[0] += wv * __uint_as_float(v.x << 16);
        acc[1] += wv * __uint_as_float(v.x & 0xffff0000u);
        acc[2] += wv * __uint_as_float(v.y << 16);
        acc[3] += wv * __uint_as_float(v.y & 0xffff0000u);
        acc[4] += wv * __uint_as_float(v.z << 16);
        acc[5] += wv * __uint_as_float(v.z & 0xffff0000u);
        acc[6] += wv * __uint_as_float(v.w << 16);
        acc[7] += wv * __uint_as_float(v.w & 0xffff0000u);
    }
    #pragma unroll
    for (int k = 0; k < 8; ++k) {
        acc[k] += __shfl_xor(acc[k], 8);
        acc[k] += __shfl_xor(acc[k], 16);
        acc[k] += __shfl_xor(acc[k], 32);
    }
    if (lane < 8) {
        float4 a = {acc[0] + bv0.x, acc[1] + bv0.y, acc[2] + bv0.z, acc[3] + bv0.w};
        float4 b = {acc[4] + bv1.x, acc[5] + bv1.y, acc[6] + bv1.z, acc[7] + bv1.w};
        *reinterpret_cast<float4*>(out + (size_t)row * 64 + q * 8) = a;
        *reinterpret_cast<float4*>(out + (size_t)row * 64 + q * 8 + 4) = b;
    }
}

// ---------------- MFMA GEMMs (bf16 in, f32 acc) ----------------
// No LDS: A-frags direct from global (rows block-exclusive, full-line reads);
// B-frags from packed W (L1/L2-hot). k-mapping shared by A and B -> permutation-safe.

// gemm1: s2[N,128] @ W1[128,256] + b1, relu -> h[N,256] bf16.
// 256 thr = 4 waves (2x2): wave rows 32, cols 128 -> 2 Mtiles x 8 Ntiles x 4 K-steps.
__global__ __launch_bounds__(256) void gemm1_mfma(
        const ushort* __restrict__ s2, const ushort* __restrict__ w1p,
        const float* __restrict__ b1, ushort* __restrict__ h) {
    int tx = threadIdx.x;
    int wave = tx >> 6, l = tx & 63;
    int wm = wave >> 1, wn = wave & 1;
    int row0 = blockIdx.x * 64 + wm * 32;
    int lo = l & 15, hi = l >> 4;
    bf16x8 a[2][4];
    #pragma unroll
    for (int mt = 0; mt < 2; ++mt) {
        int r = row0 + mt * 16 + lo;
        bool ok = r < NN;
        const bf16x8* base = reinterpret_cast<const bf16x8*>(s2 + (size_t)(ok ? r : 0) * 128);
        #pragma unroll
        for (int kk = 0; kk < 4; ++kk) {
            bf16x8 v = base[kk * 4 + hi];
            if (!ok) v = bf16x8{0, 0, 0, 0, 0, 0, 0, 0};
            a[mt][kk] = v;
        }
    }
    #pragma unroll
    for (int t = 0; t < 8; ++t) {
        int nt = wn * 8 + t;
        f32x4 acc0 = {0.f, 0.f, 0.f, 0.f};
        f32x4 acc1 = {0.f, 0.f, 0.f, 0.f};
        #pragma unroll
        for (int kk = 0; kk < 4; ++kk) {
            bf16x8 b = *reinterpret_cast<const bf16x8*>(w1p + (((nt * 4 + kk) * 64 + l) << 3));
            acc0 = __builtin_amdgcn_mfma_f32_16x16x32_bf16(a[0][kk], b, acc0, 0, 0, 0);
            acc1 = __builtin_amdgcn_mfma_f32_16x16x32_bf16(a[1][kk], b, acc1, 0, 0, 0);
        }
        int col = nt * 16 + lo;
        float bias = b1[col];
        #pragma unroll
        for (int r = 0; r < 4; ++r) {
            int row = row0 + hi * 4 + r;
            if (row < NN) h[(size_t)row * 256 + col] = f2bf(fmaxf(acc0[r] + bias, 0.f));
        }
        #pragma unroll
        for (int r = 0; r < 4; ++r) {
            int row = row0 + 16 + hi * 4 + r;
            if (row < NN) h[(size_t)row * 256 + col] = f2bf(fmaxf(acc1[r] + bias, 0.f));
        }
    }
}

// gemm2: h[N,256] @ W2[256,64] -> g[N,64] bf16. 4 waves x 16 rows; 4 Ntiles x 8 K-steps.
__global__ __launch_bounds__(256) void gemm2_mfma(
        const ushort* __restrict__ h, const ushort* __restrict__ w2p,
        ushort* __restrict__ g) {
    int tx = threadIdx.x;
    int wave = tx >> 6, l = tx & 63;
    int row0 = blockIdx.x * 64 + wave * 16;
    int lo = l & 15, hi = l >> 4;
    int r0 = row0 + lo;
    bool ok = r0 < NN;
    const bf16x8* base = reinterpret_cast<const bf16x8*>(h + (size_t)(ok ? r0 : 0) * 256);
    bf16x8 a[8];
    #pragma unroll
    for (int kk = 0; kk < 8; ++kk) {
        bf16x8 v = base[kk * 4 + hi];
        if (!ok) v = bf16x8{0, 0, 0, 0, 0, 0, 0, 0};
        a[kk] = v;
    }
    #pragma unroll
    for (int t = 0; t < 4; ++t) {
        f32x4 acc = {0.f, 0.f, 0.f, 0.f};
        #pragma unroll
        for (int kk = 0; kk < 8; ++kk) {
            bf16x8 b = *reinterpret_cast<const bf16x8*>(w2p + (((t * 8 + kk) * 64 + l) << 3));
            acc = __builtin_amdgcn_mfma_f32_16x16x32_bf16(a[kk], b, acc, 0, 0, 0);
        }
        int col = t * 16 + lo;
        #pragma unroll
        for (int r = 0; r < 4; ++r) {
            int row = row0 + hi * 4 + r;
            if (row < NN) g[(size_t)row * 64 + col] = f2bf(acc[r]);
        }
    }
}

// ---------------- launch ----------------

extern "C" void kernel_launch(void* const* d_in, const int* in_sizes, int n_in,
                              void* d_out, int out_size, void* d_ws, size_t ws_size,
                              hipStream_t stream) {
    const float* x     = (const float*)d_in[0];
    const int*   ei    = (const int*)d_in[1];
    const float* ew_in = (const float*)d_in[2];
    const float* W1    = (const float*)d_in[3];
    const float* b1    = (const float*)d_in[4];
    const float* W2    = (const float*)d_in[5];
    const float* b2    = (const float*)d_in[6];
    float* outp = (float*)d_out;

    const int n = NN, e = NE;
    const int* dst = ei;
    const int* src = ei + e;

    char* ws = (char*)d_ws;
    size_t off = 0;
    auto alloc = [&](size_t bytes) {
        void* p = ws + off;
        off += (bytes + 255) & ~size_t(255);
        return p;
    };
    int2*  ep     = (int2*)alloc(sizeof(int2) * (size_t)e);
    int*   bcnt   = (int*)alloc(sizeof(int) * NBUK);
    int*   bstart = (int*)alloc(sizeof(int) * (NBUK + 1));
    int*   gtail  = (int*)alloc(sizeof(int) * NBUK);
    int*   rp     = (int*)alloc(sizeof(int) * (size_t)(n + 1));
    ushort* w1p   = (ushort*)alloc(sizeof(ushort) * 32768);
    ushort* w2p   = (ushort*)alloc(sizeof(ushort) * 16384);
    float* sbuf   = (float*)alloc(sizeof(float) * (size_t)n * 128);   // 51.2 MB region
    float* hbuf   = (float*)alloc(sizeof(float) * (size_t)n * 256);   // 102.4 MB region
    // aliases:
    ushort* x2 = (ushort*)hbuf;                                   // bf16 x, dead before h written
    uint2*  stg = (uint2*)((char*)hbuf + (size_t)n * 128 * 2);    // staging, dead before h written
    ushort* hb  = (ushort*)hbuf;                                  // h bf16 [N,256] (51.2 MB)
    ushort* s2  = (ushort*)sbuf;                                  // s bf16 [N,128] (25.6 MB)
    ushort* g2  = (ushort*)sbuf;                                  // g bf16 [N,64]; s2 dead after gemm1

    hipMemsetAsync(bcnt, 0, sizeof(int) * NBUK, stream);
    bcount_kernel<<<P1_BLOCKS, 512, 0, stream>>>(dst, bcnt);
    bscan_kernel<<<1, 256, 0, stream>>>(bcnt, bstart, gtail, rp);
    cast_bf16_kernel<<<(n * 128 / 8 + 255) / 256, 256, 0, stream>>>(x, x2, n * 128 / 8);
    pack_w_kernel<<<128, 256, 0, stream>>>(W1, W2, w1p, w2p);
    part1_kernel<<<P1_BLOCKS, 512, 0, stream>>>(dst, src, ew_in, gtail, stg);
    part2_kernel<<<NBUK, 512, 0, stream>>>(stg, bstart, rp, ep);

    // layer 1: s = A @ x (bf16) ; h = relu(s @ W1 + b1) (bf16, MFMA)
    spmm_x_bf16<<<(n + 3) / 4, 256, 0, stream>>>(ep, rp, (const uint4*)x2, (uint4*)s2, n);
    gemm1_mfma<<<(n + 63) / 64, 256, 0, stream>>>(s2, w1p, b1, hb);

    // layer 2: g = h @ W2 (bf16, MFMA) ; out = A @ g + b2
    gemm2_mfma<<<(n + 63) / 64, 256, 0, stream>>>(hb, w2p, g2);
    spmm_g_bf16<<<(n + 3) / 4, 256, 0, stream>>>(ep, rp, (const uint4*)g2, b2, outp, n);
}